// Round 4
// baseline (2644.632 us; speedup 1.0000x reference)
//
#include <hip/hip_runtime.h>
#include <hip/hip_bf16.h>
#include <math.h>

constexpr int Bb = 128, Tt = 24, Vv = 10000, Ee = 512, Hh = 512, Ff = 2048, Aa = 512, Pp = 196;
constexpr int XS = Ee + 2 * Hh; // 1536: per-(t,b) row = [h1 | emb | ctx]
constexpr int NFC = 10112;      // fc weight rows padded to multiple of 128

typedef __attribute__((ext_vector_type(8))) short bhalf8;   // 8 bf16 = 4 VGPRs (MFMA A/B frag)
typedef __attribute__((ext_vector_type(4))) float fx4;      // MFMA C/D frag
typedef __attribute__((ext_vector_type(8))) short short8;

__device__ __forceinline__ ushort f2bf(float f) {
    __hip_bfloat16 h = __float2bfloat16(f);
    return *reinterpret_cast<ushort*>(&h);
}
__device__ __forceinline__ float bf2f(ushort u) {
    __hip_bfloat16 h = *reinterpret_cast<__hip_bfloat16*>(&u);
    return __bfloat162float(h);
}
__device__ __forceinline__ float sigm_(float x) { return 1.f / (1.f + __expf(-x)); }
__device__ __forceinline__ float tanh_(float x) {
    x = fminf(fmaxf(x, -15.f), 15.f);
    float e = __expf(2.f * x);
    return (e - 1.f) / (e + 1.f);
}

// async global->LDS, 16B per lane (wave-uniform LDS base + lane*16)
__device__ __forceinline__ void gld_lds16(const void* g, void* l) {
    __builtin_amdgcn_global_load_lds(
        (const __attribute__((address_space(1))) unsigned int*)g,
        (__attribute__((address_space(3))) unsigned int*)l, 16, 0, 0);
}

// ---------------------------------------------------------------------------
// LDS-staged bf16 MFMA GEMM (m97 structure): C[M,N] = A[M,K] @ B[N,K]^T + bias.
// Block = 256 thr (4 waves, 2x2), tile 128x128, BK=32, single-buffer LDS.
// SWZ: XCD-chunked bijective block swizzle. 0 = m-major chunks, 1 = n-major.
// OUT_MODE: 0 = fp32 store, 1 = bf16 store, 2 = fp32 store remapped
// (row m = t*128+b -> out[(b*T+t)*V + col]) with col<N store guard (fc tail).
// ---------------------------------------------------------------------------
template<bool AFP32, int OUT_MODE, int SWZ>
__global__ __launch_bounds__(256) void mfma_gemm_staged(
    const void* __restrict__ Av, int lda,
    const ushort* __restrict__ B, int ldb, int K,
    const float* __restrict__ bias1, const float* __restrict__ bias2,
    void* __restrict__ Cv, int ldc, int N)
{
    __shared__ __align__(16) ushort Alds[128 * 32];
    __shared__ __align__(16) ushort Blds[128 * 32];

    const int tid = threadIdx.x;
    const int lane = tid & 63, wave = tid >> 6;
    const int row16 = lane & 15, quad = lane >> 4;
    const int wm = wave >> 1, wn = wave & 1;

    int lm, ln;
    {
        const int nx = gridDim.x, ny = gridDim.y;
        const int flat = blockIdx.y * nx + blockIdx.x;
        const int total = nx * ny;
        if ((total & 7) == 0) {
            const int T = (flat & 7) * (total >> 3) + (flat >> 3);
            if (SWZ == 1) { ln = T / ny; lm = T - ln * ny; }
            else          { lm = T / nx; ln = T - lm * nx; }
        } else { lm = blockIdx.y; ln = blockIdx.x; }
    }
    const int n0 = ln * 128, m0 = lm * 128;

    const int sr = tid >> 2, sc = (tid & 3) * 8;

    const ushort* A16s0 = nullptr; const ushort* A16s1 = nullptr;
    const float*  A32s0 = nullptr; const float*  A32s1 = nullptr;
    if (AFP32) {
        A32s0 = (const float*)Av + (size_t)(m0 + sr) * lda + sc;
        A32s1 = (const float*)Av + (size_t)(m0 + 64 + sr) * lda + sc;
    } else {
        A16s0 = (const ushort*)Av + (size_t)(m0 + sr) * lda + sc;
        A16s1 = (const ushort*)Av + (size_t)(m0 + 64 + sr) * lda + sc;
    }
    const ushort* Bs0 = B + (size_t)(n0 + sr) * ldb + sc;
    const ushort* Bs1 = B + (size_t)(n0 + 64 + sr) * ldb + sc;
    ushort* Ad0 = Alds + sr * 32 + sc;
    ushort* Ad1 = Alds + (64 + sr) * 32 + sc;
    ushort* Bd0 = Blds + sr * 32 + sc;
    ushort* Bd1 = Blds + (64 + sr) * 32 + sc;

    const ushort* Afr = Alds + (wm * 64 + row16) * 32 + quad * 8;
    const ushort* Bfr = Blds + (wn * 64 + row16) * 32 + quad * 8;

    fx4 acc[4][4] = {};

    for (int k0 = 0; k0 < K; k0 += 32) {
        if (AFP32) {
            fx4 u0 = *(const fx4*)(A32s0 + k0);
            fx4 u1 = *(const fx4*)(A32s0 + k0 + 4);
            fx4 u2 = *(const fx4*)(A32s1 + k0);
            fx4 u3 = *(const fx4*)(A32s1 + k0 + 4);
            bhalf8 v0, v1;
#pragma unroll
            for (int j = 0; j < 4; ++j) {
                v0[j] = (short)f2bf(u0[j]); v0[4 + j] = (short)f2bf(u1[j]);
                v1[j] = (short)f2bf(u2[j]); v1[4 + j] = (short)f2bf(u3[j]);
            }
            *(bhalf8*)Ad0 = v0;
            *(bhalf8*)Ad1 = v1;
        } else {
            gld_lds16(A16s0 + k0, Ad0);
            gld_lds16(A16s1 + k0, Ad1);
        }
        gld_lds16(Bs0 + k0, Bd0);
        gld_lds16(Bs1 + k0, Bd1);
        __syncthreads();

        bhalf8 af[4], bfv[4];
#pragma unroll
        for (int f = 0; f < 4; ++f) {
            af[f]  = *(const bhalf8*)(Afr + f * 16 * 32);
            bfv[f] = *(const bhalf8*)(Bfr + f * 16 * 32);
        }
#pragma unroll
        for (int i = 0; i < 4; ++i)
#pragma unroll
            for (int j = 0; j < 4; ++j)
                acc[i][j] = __builtin_amdgcn_mfma_f32_16x16x32_bf16(af[i], bfv[j], acc[i][j], 0, 0, 0);
        __syncthreads();
    }

#pragma unroll
    for (int j = 0; j < 4; ++j) {
        const int col = n0 + wn * 64 + j * 16 + row16;
        if (OUT_MODE == 2 && col >= N) continue;
        const float badd = (bias1 ? bias1[col] : 0.f) + (bias2 ? bias2[col] : 0.f);
#pragma unroll
        for (int i = 0; i < 4; ++i) {
            const int mb = m0 + wm * 64 + i * 16 + quad * 4;
#pragma unroll
            for (int r = 0; r < 4; ++r) {
                const int m = mb + r;
                const float v = acc[i][j][r] + badd;
                if (OUT_MODE == 0)      ((float*)Cv)[(size_t)m * ldc + col] = v;
                else if (OUT_MODE == 1) ((ushort*)Cv)[(size_t)m * ldc + col] = f2bf(v);
                else { int t = m >> 7, b = m & 127; ((float*)Cv)[((size_t)(b * Tt + t)) * Vv + col] = v; }
            }
        }
    }
}

// ---------------------------------------------------------------------------
// K-split fused dual-GEMM + LSTM cell. grid (8, 32) = 256 blocks, 256 thr.
// Block output: 16 b-rows x 16 j x 4 gates. 4 waves split concat-K (1024)
// into 4 quarters; LDS combine; wave w epilogues acc reg r = w.
// ---------------------------------------------------------------------------
template<bool HAS_PRE>
__global__ __launch_bounds__(256) void gates_cell_ksplit(
    const ushort* __restrict__ A1, int lda1, const ushort* __restrict__ B1,
    const ushort* __restrict__ A2, const ushort* __restrict__ B2,
    const float* __restrict__ pre,
    const float* __restrict__ bias_a, const float* __restrict__ bias_b,
    float* __restrict__ cstate,
    ushort* __restrict__ hout,
    ushort* __restrict__ xs_slot)
{
    __shared__ float part[4][4][4][64];  // [wave][gate][reg][lane] = 16 KB
    const int tid = threadIdx.x, lane = tid & 63, wave = tid >> 6;
    const int row16 = lane & 15, quad = lane >> 4;
    const int m0 = blockIdx.x * 16;
    const int j0 = blockIdx.y * 16;
    const int mat = wave >> 1, klo = (wave & 1) * 256;

    const ushort* Abase = mat ? A2 : A1;
    const int lda = mat ? Hh : lda1;
    const ushort* ap = Abase + (size_t)(m0 + row16) * lda + klo + quad * 8;
    const ushort* Bsel = mat ? B2 : B1;
    const ushort* bp[4];
#pragma unroll
    for (int f = 0; f < 4; ++f)
        bp[f] = Bsel + (size_t)(f * Hh + j0 + row16) * Hh + klo + quad * 8;

    fx4 acc[4] = {};
#pragma unroll 2
    for (int k0 = 0; k0 < 256; k0 += 32) {
        bhalf8 a = *(const bhalf8*)(ap + k0);
#pragma unroll
        for (int f = 0; f < 4; ++f)
            acc[f] = __builtin_amdgcn_mfma_f32_16x16x32_bf16(a, *(const bhalf8*)(bp[f] + k0), acc[f], 0, 0, 0);
    }
#pragma unroll
    for (int f = 0; f < 4; ++f)
#pragma unroll
        for (int r = 0; r < 4; ++r)
            part[wave][f][r][lane] = acc[f][r];
    __syncthreads();

    const int r = wave;
    const int j = j0 + row16;
    const int b = m0 + quad * 4 + r;
    float g4[4];
#pragma unroll
    for (int f = 0; f < 4; ++f)
        g4[f] = part[0][f][r][lane] + part[1][f][r][lane]
              + part[2][f][r][lane] + part[3][f][r][lane];
    float gi = g4[0], gf = g4[1], gg = g4[2], go = g4[3];
    if (HAS_PRE) {
        const float* pr = pre + (size_t)b * (4 * Hh) + j;
        gi += pr[0]; gf += pr[Hh]; gg += pr[2 * Hh]; go += pr[3 * Hh];
    } else {
        gi += bias_a[j] + bias_b[j];
        gf += bias_a[Hh + j] + bias_b[Hh + j];
        gg += bias_a[2 * Hh + j] + bias_b[2 * Hh + j];
        go += bias_a[3 * Hh + j] + bias_b[3 * Hh + j];
    }
    const int idx = b * Hh + j;
    float c = sigm_(gf) * cstate[idx] + sigm_(gi) * tanh_(gg);
    cstate[idx] = c;
    float h = sigm_(go) * tanh_(c);
    hout[idx] = f2bf(h);
    if (xs_slot) xs_slot[(size_t)b * XS + j] = f2bf(h);
}

// ---------------------------------------------------------------------------
// Fused per-step attention: 256 blocks x 1024 thr. Block = (b = bid>>1, h-half).
// Each block redundantly computes atth + scores + softmax for its b (cheap,
// featfp is L3-resident), then PV for its 256-h half. One launch per step.
// ---------------------------------------------------------------------------
__global__ __launch_bounds__(1024) void attention_fused_kernel(
    const ushort* __restrict__ featfp,
    const ushort* __restrict__ h1cur,
    const ushort* __restrict__ attWh_t,
    const float* __restrict__ att_bh, const float* __restrict__ att_v,
    const float* __restrict__ att_bv, const float* __restrict__ proj_b,
    ushort* __restrict__ xs_t)
{
    __shared__ float h1s[Hh];
    __shared__ float kpart[2][Aa];
    __shared__ float atth[Aa];
    __shared__ float scs[200];
    __shared__ float part[4][256];
    const int b = blockIdx.x >> 1, hh = blockIdx.x & 1;
    const int tid = threadIdx.x, lane = tid & 63, wave = tid >> 6;

    if (tid < Hh) h1s[tid] = bf2f(h1cur[b * Hh + tid]);
    __syncthreads();

    // atth[a] = att_bh[a] + h1 . Wh[:,a]; thread -> (a = tid&511, k-half)
    {
        const int a = tid & 511, kh = tid >> 9;
        const ushort* wr = attWh_t + (size_t)a * Hh + kh * 256;
        const float* hp = h1s + kh * 256;
        float s = 0.f;
#pragma unroll 4
        for (int k0 = 0; k0 < 256; k0 += 8) {
            bhalf8 w = *(const bhalf8*)(wr + k0);
#pragma unroll
            for (int jj = 0; jj < 8; ++jj) s += hp[k0 + jj] * bf2f((ushort)w[jj]);
        }
        kpart[kh][a] = s;
    }
    __syncthreads();
    if (tid < Aa) atth[tid] = kpart[0][tid] + kpart[1][tid] + att_bh[tid];
    __syncthreads();

    // scores: 16 waves stripe the 196 p-rows; lane owns a = lane*8..+7
    float attv8[8], atth8[8];
#pragma unroll
    for (int jj = 0; jj < 8; ++jj) { attv8[jj] = att_v[lane * 8 + jj]; atth8[jj] = atth[lane * 8 + jj]; }
    const ushort* fa = featfp + (size_t)b * Pp * 1024;
    for (int p = wave; p < Pp; p += 16) {
        bhalf8 v = *(const bhalf8*)(fa + (size_t)p * 1024 + lane * 8);
        float partial = 0.f;
#pragma unroll
        for (int jj = 0; jj < 8; ++jj) partial += tanh_(bf2f((ushort)v[jj]) + atth8[jj]) * attv8[jj];
#pragma unroll
        for (int o = 32; o > 0; o >>= 1) partial += __shfl_down(partial, o);
        if (lane == 0) scs[p] = partial + att_bv[0];
    }
    __syncthreads();

    if (tid < 64) { // single-wave softmax over P=196
        float m = -1e30f;
        for (int p = lane; p < Pp; p += 64) m = fmaxf(m, scs[p]);
#pragma unroll
        for (int o = 32; o > 0; o >>= 1) m = fmaxf(m, __shfl_down(m, o));
        m = __shfl(m, 0);
        float s = 0.f;
        for (int p = lane; p < Pp; p += 64) { float e = __expf(scs[p] - m); scs[p] = e; s += e; }
#pragma unroll
        for (int o = 32; o > 0; o >>= 1) s += __shfl_down(s, o);
        s = __shfl(s, 0);
        float inv = 1.f / s;
        for (int p = lane; p < Pp; p += 64) scs[p] *= inv;
    }
    __syncthreads();

    // PV for this block's 256-h half: thread -> (hl = tid&255, p-quarter)
    const int hl = tid & 255, pq = tid >> 8;
    const int h = hh * 256 + hl;
    const ushort* fpx = featfp + (size_t)b * Pp * 1024 + 512 + h;
    float s = 0.f;
    const int p1 = pq * 49 + 49;
#pragma unroll 4
    for (int p = pq * 49; p < p1; ++p) s += scs[p] * bf2f(fpx[(size_t)p * 1024]);
    part[pq][hl] = s;
    __syncthreads();
    if (tid < 256) {
        float v = part[0][tid] + part[1][tid] + part[2][tid] + part[3][tid] + proj_b[hh * 256 + tid];
        xs_t[(size_t)b * XS + Ee + Hh + hh * 256 + tid] = f2bf(fmaxf(v, 0.f));
    }
}

// ---------------------------------------------------------------------------
__global__ __launch_bounds__(256) void transpose_f32_bf16(
    const float* __restrict__ in, ushort* __restrict__ out, int R, int C)
{
    __shared__ float tile[32][33];
    const int tx = threadIdx.x & 31, ty = threadIdx.x >> 5;
    const int c0 = blockIdx.x * 32, r0 = blockIdx.y * 32;
    for (int i = ty; i < 32; i += 8) {
        int r = r0 + i, c = c0 + tx;
        tile[i][tx] = (r < R && c < C) ? in[(size_t)r * C + c] : 0.f;
    }
    __syncthreads();
    for (int i = ty; i < 32; i += 8) {
        int oc = c0 + i, orr = r0 + tx;
        if (oc < C && orr < R) out[(size_t)oc * R + orr] = f2bf(tile[tx][i]);
    }
}

// batched LSTM-weight slice converts: 5 slices, all [2048 x 512] bf16 out
__global__ __launch_bounds__(256) void convert5_kernel(
    const float* __restrict__ W_ih0, const float* __restrict__ W_hh0,
    const float* __restrict__ W_ih1, const float* __restrict__ W_hh1,
    ushort* __restrict__ Wemb0, ushort* __restrict__ Wctx0,
    ushort* __restrict__ Whh0, ushort* __restrict__ Wih1,
    ushort* __restrict__ Whh1)
{
    const float* in; int ld, c0; ushort* out;
    switch (blockIdx.y) {
        case 0:  in = W_ih0; ld = Ee + Hh; c0 = 0;  out = Wemb0; break;
        case 1:  in = W_ih0; ld = Ee + Hh; c0 = Ee; out = Wctx0; break;
        case 2:  in = W_hh0; ld = Hh;      c0 = 0;  out = Whh0;  break;
        case 3:  in = W_ih1; ld = Hh;      c0 = 0;  out = Wih1;  break;
        default: in = W_hh1; ld = Hh;      c0 = 0;  out = Whh1;  break;
    }
    int idx = blockIdx.x * 256 + threadIdx.x;
    if (idx >= 4 * Hh * 512) return;
    int r = idx >> 9, c = idx & 511;
    out[idx] = f2bf(in[(size_t)r * ld + c0 + c]);
}

// grid-stride fp32 -> bf16 bulk convert (short8 stores, 16B/lane)
__global__ __launch_bounds__(256) void convert_bulk_kernel(
    const float* __restrict__ in, ushort* __restrict__ out, long n)
{
    long stride = (long)gridDim.x * 256 * 8;
    for (long i = ((long)blockIdx.x * 256 + threadIdx.x) * 8; i < n; i += stride) {
        fx4 u0 = *(const fx4*)(in + i);
        fx4 u1 = *(const fx4*)(in + i + 4);
        short8 v;
#pragma unroll
        for (int j = 0; j < 4; ++j) { v[j] = (short)f2bf(u0[j]); v[4 + j] = (short)f2bf(u1[j]); }
        *(short8*)(out + i) = v;
    }
}

__global__ __launch_bounds__(256) void emb_fill_kernel(
    const float* __restrict__ emb, const int* __restrict__ captions,
    ushort* __restrict__ xs)
{
    int idx = blockIdx.x * 256 + threadIdx.x;
    if (idx >= Tt * Bb * Ee) return;
    int e = idx % Ee, rb = idx / Ee;
    int t = rb / Bb, b = rb % Bb;
    int tok = captions[b * Tt + t];
    xs[((size_t)(t * Bb + b)) * XS + Ee + e] = f2bf(emb[(size_t)tok * Ee + e]);
}

__global__ __launch_bounds__(256) void layernorm_kernel(
    const float* __restrict__ x, const float* __restrict__ g,
    const float* __restrict__ beta, ushort* __restrict__ y)
{
    __shared__ float red[4];
    const int row = blockIdx.x;
    const float* xr = x + (size_t)row * Hh;
    const int tid = threadIdx.x, lane = tid & 63, wave = tid >> 6;
    float v0 = xr[tid], v1 = xr[tid + 256];
    float s = v0 + v1;
#pragma unroll
    for (int o = 32; o > 0; o >>= 1) s += __shfl_down(s, o);
    if (lane == 0) red[wave] = s;
    __syncthreads();
    float mu = (red[0] + red[1] + red[2] + red[3]) / 512.f;
    float d0 = v0 - mu, d1 = v1 - mu;
    float q = d0 * d0 + d1 * d1;
#pragma unroll
    for (int o = 32; o > 0; o >>= 1) q += __shfl_down(q, o);
    __syncthreads();
    if (lane == 0) red[wave] = q;
    __syncthreads();
    float var = (red[0] + red[1] + red[2] + red[3]) / 512.f;
    float inv = 1.f / sqrtf(var + 1e-5f);
    y[(size_t)row * Hh + tid]       = f2bf(d0 * inv * g[tid] + beta[tid]);
    y[(size_t)row * Hh + tid + 256] = f2bf(d1 * inv * g[tid + 256] + beta[tid + 256]);
}

// ---------------------------------------------------------------------------
extern "C" void kernel_launch(void* const* d_in, const int* in_sizes, int n_in,
                              void* d_out, int out_size, void* d_ws, size_t ws_size,
                              hipStream_t stream)
{
    const float* features = (const float*)d_in[0];
    const int*   captions = (const int*)d_in[1];
    const float* emb      = (const float*)d_in[2];
    const float* att_Wf   = (const float*)d_in[3];
    const float* att_bf   = (const float*)d_in[4];
    const float* att_Wh   = (const float*)d_in[5];
    const float* att_bh   = (const float*)d_in[6];
    const float* att_v    = (const float*)d_in[7];
    const float* att_bv   = (const float*)d_in[8];
    const float* proj_W   = (const float*)d_in[9];
    const float* proj_b   = (const float*)d_in[10];
    const float* W_ih0    = (const float*)d_in[11];
    const float* W_hh0    = (const float*)d_in[12];
    const float* b_ih0    = (const float*)d_in[13];
    const float* b_hh0    = (const float*)d_in[14];
    const float* W_ih1    = (const float*)d_in[15];
    const float* W_hh1    = (const float*)d_in[16];
    const float* b_ih1    = (const float*)d_in[17];
    const float* b_hh1    = (const float*)d_in[18];
    const float* ln_g     = (const float*)d_in[19];
    const float* ln_b     = (const float*)d_in[20];
    const float* skip_W   = (const float*)d_in[21];
    const float* skip_b   = (const float*)d_in[22];
    const float* fc_W     = (const float*)d_in[23];
    const float* fc_b     = (const float*)d_in[24];

    char* base = (char*)d_ws;
    size_t off = 0;
    auto alloc = [&](size_t bytes) { char* p = base + off; off = (off + bytes + 255) & ~(size_t)255; return p; };

    float*  c0      = (float*)alloc(Bb * Hh * 4);
    float*  c1      = (float*)alloc(Bb * Hh * 4);
    ushort* h0b[2]  = {(ushort*)alloc(Bb * Hh * 2), (ushort*)alloc(Bb * Hh * 2)};
    ushort* h1b[2]  = {(ushort*)alloc(Bb * Hh * 2), (ushort*)alloc(Bb * Hh * 2)};
    size_t state_bytes = off;

    // NOTE: attWf_t and projW_t must stay contiguous (fused [1024,2048] B matrix)
    ushort* attWf_t  = (ushort*)alloc((size_t)Aa * Ff * 2);
    ushort* projW_t  = (ushort*)alloc((size_t)Hh * Ff * 2);
    ushort* attWh_t  = (ushort*)alloc((size_t)Aa * Hh * 2);
    ushort* skipW_t  = (ushort*)alloc((size_t)Hh * XS * 2);
    ushort* fcW_t    = (ushort*)alloc((size_t)NFC * Hh * 2);
    ushort* Wemb0    = (ushort*)alloc((size_t)4 * Hh * Ee * 2);
    ushort* Wctx0    = (ushort*)alloc((size_t)4 * Hh * Hh * 2);
    ushort* Whh0     = (ushort*)alloc((size_t)4 * Hh * Hh * 2);
    ushort* Wih1     = (ushort*)alloc((size_t)4 * Hh * Hh * 2);
    ushort* Whh1     = (ushort*)alloc((size_t)4 * Hh * Hh * 2);
    ushort* featfp   = (ushort*)alloc((size_t)Bb * Pp * 1024 * 2);
    ushort* xs       = (ushort*)alloc((size_t)Tt * Bb * XS * 2);
    float*  g0pre    = (float*)alloc((size_t)Tt * Bb * 4 * Hh * 4);
    float*  skip_pre = (float*)alloc((size_t)Tt * Bb * Hh * 4);
    ushort* ln_all   = (ushort*)alloc((size_t)Tt * Bb * Hh * 2);
    float*  bias_cat = (float*)alloc(1024 * 4);

    // optional bf16 copy of features (kills in-GEMM fp32 converts); runtime-gated
    const long nfeat = (long)Bb * Pp * Ff;
    const size_t featbytes = (size_t)nfeat * 2;
    bool use_conv = (off + featbytes + 256) <= ws_size;
    ushort* feat16 = use_conv ? (ushort*)alloc(featbytes) : nullptr;

    hipMemsetAsync(d_ws, 0, state_bytes, stream);
    hipMemsetAsync(fcW_t + (size_t)Vv * Hh, 0, (size_t)(NFC - Vv) * Hh * 2, stream);
    hipMemsetAsync(bias_cat, 0, 1024 * 4, stream);
    hipMemcpyAsync(bias_cat, att_bf, Aa * 4, hipMemcpyDeviceToDevice, stream);

    dim3 blk(256);

    // ---- one-time weight prep ----
    transpose_f32_bf16<<<dim3(Aa / 32, Ff / 32), blk, 0, stream>>>(att_Wf, attWf_t, Ff, Aa);
    transpose_f32_bf16<<<dim3(Hh / 32, Ff / 32), blk, 0, stream>>>(proj_W, projW_t, Ff, Hh);
    transpose_f32_bf16<<<dim3(Aa / 32, Hh / 32), blk, 0, stream>>>(att_Wh, attWh_t, Hh, Aa);
    transpose_f32_bf16<<<dim3(Hh / 32, XS / 32), blk, 0, stream>>>(skip_W, skipW_t, XS, Hh);
    transpose_f32_bf16<<<dim3((Vv + 31) / 32, Hh / 32), blk, 0, stream>>>(fc_W, fcW_t, Hh, Vv);
    convert5_kernel<<<dim3((4 * Hh * 512 + 255) / 256, 5), blk, 0, stream>>>(
        W_ih0, W_hh0, W_ih1, W_hh1, Wemb0, Wctx0, Whh0, Wih1, Whh1);

    emb_fill_kernel<<<(Tt * Bb * Ee + 255) / 256, blk, 0, stream>>>(emb, captions, xs);

    // ---- fused feature GEMM: [25088,2048] @ [1024,2048]^T -> bf16 [25088,1024]
    if (use_conv) {
        convert_bulk_kernel<<<2048, blk, 0, stream>>>(features, feat16, nfeat);
        mfma_gemm_staged<false, 1, 0><<<dim3(1024 / 128, Bb * Pp / 128), blk, 0, stream>>>(
            feat16, Ff, attWf_t, Ff, Ff, bias_cat, nullptr, featfp, 1024, 1024);
    } else {
        mfma_gemm_staged<true, 1, 0><<<dim3(1024 / 128, Bb * Pp / 128), blk, 0, stream>>>(
            features, Ff, attWf_t, Ff, Ff, bias_cat, nullptr, featfp, 1024, 1024);
    }

    // gates0 emb-part + both biases, hoisted for all t
    mfma_gemm_staged<false, 0, 0><<<dim3(4 * Hh / 128, Tt * Bb / 128), blk, 0, stream>>>(
        xs + Ee, XS, Wemb0, Ee, Ee, b_ih0, b_hh0, g0pre, 4 * Hh, 4 * Hh);

    // ---- sequential decode loop: 3 kernels/step ----
    int cur0 = 0, cur1 = 0;
    for (int t = 0; t < Tt; ++t) {
        ushort* xs_t = xs + (size_t)t * Bb * XS;

        attention_fused_kernel<<<2 * Bb, dim3(1024), 0, stream>>>(
            featfp, h1b[cur1], attWh_t, att_bh, att_v, att_bv, proj_b, xs_t);

        gates_cell_ksplit<true><<<dim3(8, 32), blk, 0, stream>>>(
            xs_t + Ee + Hh, XS, Wctx0,
            h0b[cur0], Whh0,
            g0pre + (size_t)t * Bb * 4 * Hh, nullptr, nullptr,
            c0, h0b[cur0 ^ 1], nullptr);

        gates_cell_ksplit<false><<<dim3(8, 32), blk, 0, stream>>>(
            h0b[cur0 ^ 1], Hh, Wih1,
            h1b[cur1], Whh1,
            nullptr, b_ih1, b_hh1,
            c1, h1b[cur1 ^ 1], xs_t);
        cur0 ^= 1; cur1 ^= 1;
    }

    // ---- tail: skip GEMM -> LN -> fc GEMM ----
    mfma_gemm_staged<false, 0, 0><<<dim3(Hh / 128, Tt * Bb / 128), blk, 0, stream>>>(
        xs, XS, skipW_t, XS, XS, skip_b, nullptr, skip_pre, Hh, Hh);

    layernorm_kernel<<<Tt * Bb, blk, 0, stream>>>(skip_pre, ln_g, ln_b, ln_all);

    mfma_gemm_staged<false, 2, 1><<<dim3(NFC / 128, Tt * Bb / 128), blk, 0, stream>>>(
        ln_all, Hh, fcW_t, Hh, Hh, fc_b, nullptr, (float*)d_out, Vv, Vv);
}

// Round 5
// 2079.287 us; speedup vs baseline: 1.2719x; 1.2719x over previous
//
#include <hip/hip_runtime.h>
#include <hip/hip_bf16.h>
#include <math.h>

constexpr int Bb = 128, Tt = 24, Vv = 10000, Ee = 512, Hh = 512, Ff = 2048, Aa = 512, Pp = 196;
constexpr int XS = Ee + 2 * Hh; // 1536: per-(t,b) row = [h1 | emb | ctx]
constexpr int NFC = 10112;      // fc weight rows padded to multiple of 128
constexpr int PT = 224;         // fprojT p-stride (196 padded to 28*8, 16B-aligned rows)

typedef __attribute__((ext_vector_type(8))) short bhalf8;   // 8 bf16 = 4 VGPRs (MFMA A/B frag)
typedef __attribute__((ext_vector_type(4))) float fx4;      // MFMA C/D frag
typedef __attribute__((ext_vector_type(8))) short short8;

__device__ __forceinline__ ushort f2bf(float f) {
    __hip_bfloat16 h = __float2bfloat16(f);
    return *reinterpret_cast<ushort*>(&h);
}
__device__ __forceinline__ float bf2f(ushort u) {
    __hip_bfloat16 h = *reinterpret_cast<__hip_bfloat16*>(&u);
    return __bfloat162float(h);
}
__device__ __forceinline__ float sigm_(float x) { return 1.f / (1.f + __expf(-x)); }
__device__ __forceinline__ float tanh_(float x) {
    x = fminf(fmaxf(x, -15.f), 15.f);
    float e = __expf(2.f * x);
    return (e - 1.f) / (e + 1.f);
}

// async global->LDS, 16B per lane (wave-uniform LDS base + lane*16)
__device__ __forceinline__ void gld_lds16(const void* g, void* l) {
    __builtin_amdgcn_global_load_lds(
        (const __attribute__((address_space(1))) unsigned int*)g,
        (__attribute__((address_space(3))) unsigned int*)l, 16, 0, 0);
}

// ---------------------------------------------------------------------------
// LDS-staged bf16 MFMA GEMM (m97 structure): C[M,N] = A[M,K] @ B[N,K]^T + bias.
// Block = 256 thr (4 waves, 2x2), tile 128x128, BK=32, single-buffer LDS.
// SWZ: XCD-chunked bijective block swizzle. 0 = m-major chunks, 1 = n-major.
// OUT_MODE: 0 = fp32 store, 1 = bf16 store, 2 = fp32 store remapped
// (row m = t*128+b -> out[(b*T+t)*V + col]) with col<N store guard (fc tail).
// ---------------------------------------------------------------------------
template<bool AFP32, int OUT_MODE, int SWZ>
__global__ __launch_bounds__(256) void mfma_gemm_staged(
    const void* __restrict__ Av, int lda,
    const ushort* __restrict__ B, int ldb, int K,
    const float* __restrict__ bias1, const float* __restrict__ bias2,
    void* __restrict__ Cv, int ldc, int N)
{
    __shared__ __align__(16) ushort Alds[128 * 32];
    __shared__ __align__(16) ushort Blds[128 * 32];

    const int tid = threadIdx.x;
    const int lane = tid & 63, wave = tid >> 6;
    const int row16 = lane & 15, quad = lane >> 4;
    const int wm = wave >> 1, wn = wave & 1;

    int lm, ln;
    {
        const int nx = gridDim.x, ny = gridDim.y;
        const int flat = blockIdx.y * nx + blockIdx.x;
        const int total = nx * ny;
        if ((total & 7) == 0) {
            const int T = (flat & 7) * (total >> 3) + (flat >> 3);
            if (SWZ == 1) { ln = T / ny; lm = T - ln * ny; }
            else          { lm = T / nx; ln = T - lm * nx; }
        } else { lm = blockIdx.y; ln = blockIdx.x; }
    }
    const int n0 = ln * 128, m0 = lm * 128;

    const int sr = tid >> 2, sc = (tid & 3) * 8;

    const ushort* A16s0 = nullptr; const ushort* A16s1 = nullptr;
    const float*  A32s0 = nullptr; const float*  A32s1 = nullptr;
    if (AFP32) {
        A32s0 = (const float*)Av + (size_t)(m0 + sr) * lda + sc;
        A32s1 = (const float*)Av + (size_t)(m0 + 64 + sr) * lda + sc;
    } else {
        A16s0 = (const ushort*)Av + (size_t)(m0 + sr) * lda + sc;
        A16s1 = (const ushort*)Av + (size_t)(m0 + 64 + sr) * lda + sc;
    }
    const ushort* Bs0 = B + (size_t)(n0 + sr) * ldb + sc;
    const ushort* Bs1 = B + (size_t)(n0 + 64 + sr) * ldb + sc;
    ushort* Ad0 = Alds + sr * 32 + sc;
    ushort* Ad1 = Alds + (64 + sr) * 32 + sc;
    ushort* Bd0 = Blds + sr * 32 + sc;
    ushort* Bd1 = Blds + (64 + sr) * 32 + sc;

    const ushort* Afr = Alds + (wm * 64 + row16) * 32 + quad * 8;
    const ushort* Bfr = Blds + (wn * 64 + row16) * 32 + quad * 8;

    fx4 acc[4][4] = {};

    for (int k0 = 0; k0 < K; k0 += 32) {
        if (AFP32) {
            fx4 u0 = *(const fx4*)(A32s0 + k0);
            fx4 u1 = *(const fx4*)(A32s0 + k0 + 4);
            fx4 u2 = *(const fx4*)(A32s1 + k0);
            fx4 u3 = *(const fx4*)(A32s1 + k0 + 4);
            bhalf8 v0, v1;
#pragma unroll
            for (int j = 0; j < 4; ++j) {
                v0[j] = (short)f2bf(u0[j]); v0[4 + j] = (short)f2bf(u1[j]);
                v1[j] = (short)f2bf(u2[j]); v1[4 + j] = (short)f2bf(u3[j]);
            }
            *(bhalf8*)Ad0 = v0;
            *(bhalf8*)Ad1 = v1;
        } else {
            gld_lds16(A16s0 + k0, Ad0);
            gld_lds16(A16s1 + k0, Ad1);
        }
        gld_lds16(Bs0 + k0, Bd0);
        gld_lds16(Bs1 + k0, Bd1);
        __syncthreads();

        bhalf8 af[4], bfv[4];
#pragma unroll
        for (int f = 0; f < 4; ++f) {
            af[f]  = *(const bhalf8*)(Afr + f * 16 * 32);
            bfv[f] = *(const bhalf8*)(Bfr + f * 16 * 32);
        }
#pragma unroll
        for (int i = 0; i < 4; ++i)
#pragma unroll
            for (int j = 0; j < 4; ++j)
                acc[i][j] = __builtin_amdgcn_mfma_f32_16x16x32_bf16(af[i], bfv[j], acc[i][j], 0, 0, 0);
        __syncthreads();
    }

#pragma unroll
    for (int j = 0; j < 4; ++j) {
        const int col = n0 + wn * 64 + j * 16 + row16;
        if (OUT_MODE == 2 && col >= N) continue;
        const float badd = (bias1 ? bias1[col] : 0.f) + (bias2 ? bias2[col] : 0.f);
#pragma unroll
        for (int i = 0; i < 4; ++i) {
            const int mb = m0 + wm * 64 + i * 16 + quad * 4;
#pragma unroll
            for (int r = 0; r < 4; ++r) {
                const int m = mb + r;
                const float v = acc[i][j][r] + badd;
                if (OUT_MODE == 0)      ((float*)Cv)[(size_t)m * ldc + col] = v;
                else if (OUT_MODE == 1) ((ushort*)Cv)[(size_t)m * ldc + col] = f2bf(v);
                else { int t = m >> 7, b = m & 127; ((float*)Cv)[((size_t)(b * Tt + t)) * Vv + col] = v; }
            }
        }
    }
}

// ---------------------------------------------------------------------------
// K-split fused dual-GEMM + LSTM cell. grid (8, 32) = 256 blocks, 256 thr.
// Block output: 16 b-rows x 16 j x 4 gates. 4 waves split concat-K (1024)
// into 4 quarters; LDS combine; wave w epilogues acc reg r = w.
// ---------------------------------------------------------------------------
template<bool HAS_PRE>
__global__ __launch_bounds__(256) void gates_cell_ksplit(
    const ushort* __restrict__ A1, int lda1, const ushort* __restrict__ B1,
    const ushort* __restrict__ A2, const ushort* __restrict__ B2,
    const float* __restrict__ pre,
    const float* __restrict__ bias_a, const float* __restrict__ bias_b,
    float* __restrict__ cstate,
    ushort* __restrict__ hout,
    ushort* __restrict__ xs_slot)
{
    __shared__ float part[4][4][4][64];  // [wave][gate][reg][lane] = 16 KB
    const int tid = threadIdx.x, lane = tid & 63, wave = tid >> 6;
    const int row16 = lane & 15, quad = lane >> 4;
    const int m0 = blockIdx.x * 16;
    const int j0 = blockIdx.y * 16;
    const int mat = wave >> 1, klo = (wave & 1) * 256;

    const ushort* Abase = mat ? A2 : A1;
    const int lda = mat ? Hh : lda1;
    const ushort* ap = Abase + (size_t)(m0 + row16) * lda + klo + quad * 8;
    const ushort* Bsel = mat ? B2 : B1;
    const ushort* bp[4];
#pragma unroll
    for (int f = 0; f < 4; ++f)
        bp[f] = Bsel + (size_t)(f * Hh + j0 + row16) * Hh + klo + quad * 8;

    fx4 acc[4] = {};
#pragma unroll 2
    for (int k0 = 0; k0 < 256; k0 += 32) {
        bhalf8 a = *(const bhalf8*)(ap + k0);
#pragma unroll
        for (int f = 0; f < 4; ++f)
            acc[f] = __builtin_amdgcn_mfma_f32_16x16x32_bf16(a, *(const bhalf8*)(bp[f] + k0), acc[f], 0, 0, 0);
    }
#pragma unroll
    for (int f = 0; f < 4; ++f)
#pragma unroll
        for (int r = 0; r < 4; ++r)
            part[wave][f][r][lane] = acc[f][r];
    __syncthreads();

    const int r = wave;
    const int j = j0 + row16;
    const int b = m0 + quad * 4 + r;
    float g4[4];
#pragma unroll
    for (int f = 0; f < 4; ++f)
        g4[f] = part[0][f][r][lane] + part[1][f][r][lane]
              + part[2][f][r][lane] + part[3][f][r][lane];
    float gi = g4[0], gf = g4[1], gg = g4[2], go = g4[3];
    if (HAS_PRE) {
        const float* pr = pre + (size_t)b * (4 * Hh) + j;
        gi += pr[0]; gf += pr[Hh]; gg += pr[2 * Hh]; go += pr[3 * Hh];
    } else {
        gi += bias_a[j] + bias_b[j];
        gf += bias_a[Hh + j] + bias_b[Hh + j];
        gg += bias_a[2 * Hh + j] + bias_b[2 * Hh + j];
        go += bias_a[3 * Hh + j] + bias_b[3 * Hh + j];
    }
    const int idx = b * Hh + j;
    float c = sigm_(gf) * cstate[idx] + sigm_(gi) * tanh_(gg);
    cstate[idx] = c;
    float h = sigm_(go) * tanh_(c);
    hout[idx] = f2bf(h);
    if (xs_slot) xs_slot[(size_t)b * XS + j] = f2bf(h);
}

// ---------------------------------------------------------------------------
// Attention scores: 256 blocks x 1024 thr. Block = (b = bid>>1, p-half).
// atth is precomputed (atth_all, fp32 [B,A]) -- pure streaming kernel:
// 16 waves stripe 98 p-rows; lane owns a = lane*8..+7; shuffle-reduce.
// ---------------------------------------------------------------------------
__global__ __launch_bounds__(1024) void att_scores_kernel(
    const ushort* __restrict__ featfp,
    const float* __restrict__ atth_all,
    const float* __restrict__ att_v,
    const float* __restrict__ att_bv,
    float* __restrict__ scores_g)
{
    const int b = blockIdx.x >> 1, ph = blockIdx.x & 1;
    const int tid = threadIdx.x, lane = tid & 63, wave = tid >> 6;

    float attv8[8], atth8[8];
    {
        const fx4* vp = (const fx4*)(att_v + lane * 8);
        const fx4* ap = (const fx4*)(atth_all + b * Aa + lane * 8);
        fx4 v0 = vp[0], v1 = vp[1], a0 = ap[0], a1 = ap[1];
#pragma unroll
        for (int j = 0; j < 4; ++j) {
            attv8[j] = v0[j]; attv8[4 + j] = v1[j];
            atth8[j] = a0[j]; atth8[4 + j] = a1[j];
        }
    }
    const ushort* fa = featfp + (size_t)b * Pp * 1024;
    const int pend = ph * 98 + 98;
    for (int p = ph * 98 + wave; p < pend; p += 16) {
        bhalf8 v = *(const bhalf8*)(fa + (size_t)p * 1024 + lane * 8);
        float partial = 0.f;
#pragma unroll
        for (int jj = 0; jj < 8; ++jj) partial += tanh_(bf2f((ushort)v[jj]) + atth8[jj]) * attv8[jj];
#pragma unroll
        for (int o = 32; o > 0; o >>= 1) partial += __shfl_down(partial, o);
        if (lane == 0) scores_g[b * 256 + p] = partial + att_bv[0];
    }
}

// ---------------------------------------------------------------------------
// Attention softmax+PV: 256 blocks x 1024 thr. Block = (b = bid>>1, h-half).
// Local softmax over 196 scores, zero-padded to 224. PV reads fprojT [B,H,PT]
// (p-contiguous): thread (hl, pq) sums 7 aligned bhalf8 chunks at p = pq*8+32k.
// ---------------------------------------------------------------------------
__global__ __launch_bounds__(1024) void att_pv_kernel(
    const ushort* __restrict__ fprojT,
    const float* __restrict__ scores_g,
    const float* __restrict__ proj_b,
    ushort* __restrict__ xs_t)
{
    __shared__ float scs[PT];
    __shared__ float part[4][256];
    const int b = blockIdx.x >> 1, hh = blockIdx.x & 1;
    const int tid = threadIdx.x, lane = tid & 63;

    if (tid < Pp) scs[tid] = scores_g[b * 256 + tid];
    else if (tid < PT) scs[tid] = 0.f;
    __syncthreads();

    if (tid < 64) { // single-wave softmax over P=196 (pad stays 0)
        float m = -1e30f;
        for (int p = lane; p < Pp; p += 64) m = fmaxf(m, scs[p]);
#pragma unroll
        for (int o = 32; o > 0; o >>= 1) m = fmaxf(m, __shfl_down(m, o));
        m = __shfl(m, 0);
        float s = 0.f;
        for (int p = lane; p < Pp; p += 64) { float e = __expf(scs[p] - m); scs[p] = e; s += e; }
#pragma unroll
        for (int o = 32; o > 0; o >>= 1) s += __shfl_down(s, o);
        s = __shfl(s, 0);
        float inv = 1.f / s;
        for (int p = lane; p < Pp; p += 64) scs[p] *= inv;
    }
    __syncthreads();

    const int hl = tid & 255, pq = tid >> 8;
    const int h = hh * 256 + hl;
    const ushort* row = fprojT + ((size_t)(b * Hh + h)) * PT;
    float s = 0.f;
#pragma unroll
    for (int k = 0; k < 7; ++k) {
        const int p0 = pq * 8 + k * 32;
        bhalf8 v = *(const bhalf8*)(row + p0);
#pragma unroll
        for (int j = 0; j < 8; ++j) s += scs[p0 + j] * bf2f((ushort)v[j]);
    }
    part[pq][hl] = s;
    __syncthreads();
    if (tid < 256) {
        float v = part[0][tid] + part[1][tid] + part[2][tid] + part[3][tid] + proj_b[hh * 256 + tid];
        xs_t[(size_t)b * XS + Ee + Hh + hh * 256 + tid] = f2bf(fmaxf(v, 0.f));
    }
}

// ---------------------------------------------------------------------------
// One-time: fprojT[b, h, p] = featfp[b*P+p, 512+h], p padded to PT with zeros.
// grid (7 p-tiles, 16 h-tiles, B), 256 thr, 32x32 LDS tile; both sides coalesced.
// ---------------------------------------------------------------------------
__global__ __launch_bounds__(256) void transpose_fproj_kernel(
    const ushort* __restrict__ featfp, ushort* __restrict__ fprojT)
{
    __shared__ ushort tile[32][33];
    const int tx = threadIdx.x & 31, ty = threadIdx.x >> 5;
    const int p0 = blockIdx.x * 32, h0 = blockIdx.y * 32, b = blockIdx.z;
    for (int i = ty; i < 32; i += 8) {
        int p = p0 + i;
        tile[i][tx] = (p < Pp) ? featfp[((size_t)(b * Pp + p)) * 1024 + 512 + h0 + tx] : (ushort)0;
    }
    __syncthreads();
    for (int i = ty; i < 32; i += 8) {
        int h = h0 + i, p = p0 + tx;
        fprojT[((size_t)(b * Hh + h)) * PT + p] = tile[tx][i];
    }
}

// ---------------------------------------------------------------------------
__global__ __launch_bounds__(256) void transpose_f32_bf16(
    const float* __restrict__ in, ushort* __restrict__ out, int R, int C)
{
    __shared__ float tile[32][33];
    const int tx = threadIdx.x & 31, ty = threadIdx.x >> 5;
    const int c0 = blockIdx.x * 32, r0 = blockIdx.y * 32;
    for (int i = ty; i < 32; i += 8) {
        int r = r0 + i, c = c0 + tx;
        tile[i][tx] = (r < R && c < C) ? in[(size_t)r * C + c] : 0.f;
    }
    __syncthreads();
    for (int i = ty; i < 32; i += 8) {
        int oc = c0 + i, orr = r0 + tx;
        if (oc < C && orr < R) out[(size_t)oc * R + orr] = f2bf(tile[tx][i]);
    }
}

// batched LSTM-weight slice converts: 5 slices, all [2048 x 512] bf16 out
__global__ __launch_bounds__(256) void convert5_kernel(
    const float* __restrict__ W_ih0, const float* __restrict__ W_hh0,
    const float* __restrict__ W_ih1, const float* __restrict__ W_hh1,
    ushort* __restrict__ Wemb0, ushort* __restrict__ Wctx0,
    ushort* __restrict__ Whh0, ushort* __restrict__ Wih1,
    ushort* __restrict__ Whh1)
{
    const float* in; int ld, c0; ushort* out;
    switch (blockIdx.y) {
        case 0:  in = W_ih0; ld = Ee + Hh; c0 = 0;  out = Wemb0; break;
        case 1:  in = W_ih0; ld = Ee + Hh; c0 = Ee; out = Wctx0; break;
        case 2:  in = W_hh0; ld = Hh;      c0 = 0;  out = Whh0;  break;
        case 3:  in = W_ih1; ld = Hh;      c0 = 0;  out = Wih1;  break;
        default: in = W_hh1; ld = Hh;      c0 = 0;  out = Whh1;  break;
    }
    int idx = blockIdx.x * 256 + threadIdx.x;
    if (idx >= 4 * Hh * 512) return;
    int r = idx >> 9, c = idx & 511;
    out[idx] = f2bf(in[(size_t)r * ld + c0 + c]);
}

// grid-stride fp32 -> bf16 bulk convert (short8 stores, 16B/lane)
__global__ __launch_bounds__(256) void convert_bulk_kernel(
    const float* __restrict__ in, ushort* __restrict__ out, long n)
{
    long stride = (long)gridDim.x * 256 * 8;
    for (long i = ((long)blockIdx.x * 256 + threadIdx.x) * 8; i < n; i += stride) {
        fx4 u0 = *(const fx4*)(in + i);
        fx4 u1 = *(const fx4*)(in + i + 4);
        short8 v;
#pragma unroll
        for (int j = 0; j < 4; ++j) { v[j] = (short)f2bf(u0[j]); v[4 + j] = (short)f2bf(u1[j]); }
        *(short8*)(out + i) = v;
    }
}

__global__ __launch_bounds__(256) void emb_fill_kernel(
    const float* __restrict__ emb, const int* __restrict__ captions,
    ushort* __restrict__ xs)
{
    int idx = blockIdx.x * 256 + threadIdx.x;
    if (idx >= Tt * Bb * Ee) return;
    int e = idx % Ee, rb = idx / Ee;
    int t = rb / Bb, b = rb % Bb;
    int tok = captions[b * Tt + t];
    xs[((size_t)(t * Bb + b)) * XS + Ee + e] = f2bf(emb[(size_t)tok * Ee + e]);
}

__global__ __launch_bounds__(256) void layernorm_kernel(
    const float* __restrict__ x, const float* __restrict__ g,
    const float* __restrict__ beta, ushort* __restrict__ y)
{
    __shared__ float red[4];
    const int row = blockIdx.x;
    const float* xr = x + (size_t)row * Hh;
    const int tid = threadIdx.x, lane = tid & 63, wave = tid >> 6;
    float v0 = xr[tid], v1 = xr[tid + 256];
    float s = v0 + v1;
#pragma unroll
    for (int o = 32; o > 0; o >>= 1) s += __shfl_down(s, o);
    if (lane == 0) red[wave] = s;
    __syncthreads();
    float mu = (red[0] + red[1] + red[2] + red[3]) / 512.f;
    float d0 = v0 - mu, d1 = v1 - mu;
    float q = d0 * d0 + d1 * d1;
#pragma unroll
    for (int o = 32; o > 0; o >>= 1) q += __shfl_down(q, o);
    __syncthreads();
    if (lane == 0) red[wave] = q;
    __syncthreads();
    float var = (red[0] + red[1] + red[2] + red[3]) / 512.f;
    float inv = 1.f / sqrtf(var + 1e-5f);
    y[(size_t)row * Hh + tid]       = f2bf(d0 * inv * g[tid] + beta[tid]);
    y[(size_t)row * Hh + tid + 256] = f2bf(d1 * inv * g[tid + 256] + beta[tid + 256]);
}

// ---------------------------------------------------------------------------
extern "C" void kernel_launch(void* const* d_in, const int* in_sizes, int n_in,
                              void* d_out, int out_size, void* d_ws, size_t ws_size,
                              hipStream_t stream)
{
    const float* features = (const float*)d_in[0];
    const int*   captions = (const int*)d_in[1];
    const float* emb      = (const float*)d_in[2];
    const float* att_Wf   = (const float*)d_in[3];
    const float* att_bf   = (const float*)d_in[4];
    const float* att_Wh   = (const float*)d_in[5];
    const float* att_bh   = (const float*)d_in[6];
    const float* att_v    = (const float*)d_in[7];
    const float* att_bv   = (const float*)d_in[8];
    const float* proj_W   = (const float*)d_in[9];
    const float* proj_b   = (const float*)d_in[10];
    const float* W_ih0    = (const float*)d_in[11];
    const float* W_hh0    = (const float*)d_in[12];
    const float* b_ih0    = (const float*)d_in[13];
    const float* b_hh0    = (const float*)d_in[14];
    const float* W_ih1    = (const float*)d_in[15];
    const float* W_hh1    = (const float*)d_in[16];
    const float* b_ih1    = (const float*)d_in[17];
    const float* b_hh1    = (const float*)d_in[18];
    const float* ln_g     = (const float*)d_in[19];
    const float* ln_b     = (const float*)d_in[20];
    const float* skip_W   = (const float*)d_in[21];
    const float* skip_b   = (const float*)d_in[22];
    const float* fc_W     = (const float*)d_in[23];
    const float* fc_b     = (const float*)d_in[24];

    char* base = (char*)d_ws;
    size_t off = 0;
    auto alloc = [&](size_t bytes) { char* p = base + off; off = (off + bytes + 255) & ~(size_t)255; return p; };

    float*  c0      = (float*)alloc(Bb * Hh * 4);
    float*  c1      = (float*)alloc(Bb * Hh * 4);
    ushort* h0b[2]  = {(ushort*)alloc(Bb * Hh * 2), (ushort*)alloc(Bb * Hh * 2)};
    ushort* h1b[2]  = {(ushort*)alloc(Bb * Hh * 2), (ushort*)alloc(Bb * Hh * 2)};
    size_t state_bytes = off;

    // NOTE: attWf_t and projW_t must stay contiguous (fused [1024,2048] B matrix)
    ushort* attWf_t  = (ushort*)alloc((size_t)Aa * Ff * 2);
    ushort* projW_t  = (ushort*)alloc((size_t)Hh * Ff * 2);
    ushort* attWh_t  = (ushort*)alloc((size_t)Aa * Hh * 2);
    ushort* skipW_t  = (ushort*)alloc((size_t)Hh * XS * 2);
    ushort* fcW_t    = (ushort*)alloc((size_t)NFC * Hh * 2);
    ushort* Wemb0    = (ushort*)alloc((size_t)4 * Hh * Ee * 2);
    ushort* Wctx0    = (ushort*)alloc((size_t)4 * Hh * Hh * 2);
    ushort* Whh0     = (ushort*)alloc((size_t)4 * Hh * Hh * 2);
    ushort* Wih1     = (ushort*)alloc((size_t)4 * Hh * Hh * 2);
    ushort* Whh1     = (ushort*)alloc((size_t)4 * Hh * Hh * 2);
    ushort* featfp   = (ushort*)alloc((size_t)Bb * Pp * 1024 * 2);
    ushort* fprojT   = (ushort*)alloc((size_t)Bb * Hh * PT * 2);   // 29.4 MB, [B,H,PT]
    ushort* xs       = (ushort*)alloc((size_t)Tt * Bb * XS * 2);
    float*  g0pre    = (float*)alloc((size_t)Tt * Bb * 4 * Hh * 4);
    float*  skip_pre = (float*)alloc((size_t)Tt * Bb * Hh * 4);
    ushort* ln_all   = (ushort*)alloc((size_t)Tt * Bb * Hh * 2);
    float*  bias_cat = (float*)alloc(1024 * 4);
    float*  atth_all = (float*)alloc((size_t)Bb * Aa * 4);
    float*  scores_g = (float*)alloc((size_t)Bb * 256 * 4);

    // optional bf16 copy of features (kills in-GEMM fp32 converts); runtime-gated
    const long nfeat = (long)Bb * Pp * Ff;
    const size_t featbytes = (size_t)nfeat * 2;
    bool use_conv = (off + featbytes + 256) <= ws_size;
    ushort* feat16 = use_conv ? (ushort*)alloc(featbytes) : nullptr;

    hipMemsetAsync(d_ws, 0, state_bytes, stream);
    hipMemsetAsync(fcW_t + (size_t)Vv * Hh, 0, (size_t)(NFC - Vv) * Hh * 2, stream);
    hipMemsetAsync(bias_cat, 0, 1024 * 4, stream);
    hipMemcpyAsync(bias_cat, att_bf, Aa * 4, hipMemcpyDeviceToDevice, stream);

    dim3 blk(256);

    // ---- one-time weight prep ----
    transpose_f32_bf16<<<dim3(Aa / 32, Ff / 32), blk, 0, stream>>>(att_Wf, attWf_t, Ff, Aa);
    transpose_f32_bf16<<<dim3(Hh / 32, Ff / 32), blk, 0, stream>>>(proj_W, projW_t, Ff, Hh);
    transpose_f32_bf16<<<dim3(Aa / 32, Hh / 32), blk, 0, stream>>>(att_Wh, attWh_t, Hh, Aa);
    transpose_f32_bf16<<<dim3(Hh / 32, XS / 32), blk, 0, stream>>>(skip_W, skipW_t, XS, Hh);
    transpose_f32_bf16<<<dim3((Vv + 31) / 32, Hh / 32), blk, 0, stream>>>(fc_W, fcW_t, Hh, Vv);
    convert5_kernel<<<dim3((4 * Hh * 512 + 255) / 256, 5), blk, 0, stream>>>(
        W_ih0, W_hh0, W_ih1, W_hh1, Wemb0, Wctx0, Whh0, Wih1, Whh1);

    emb_fill_kernel<<<(Tt * Bb * Ee + 255) / 256, blk, 0, stream>>>(emb, captions, xs);

    // ---- fused feature GEMM: [25088,2048] @ [1024,2048]^T -> bf16 [25088,1024]
    if (use_conv) {
        convert_bulk_kernel<<<2048, blk, 0, stream>>>(features, feat16, nfeat);
        mfma_gemm_staged<false, 1, 0><<<dim3(1024 / 128, Bb * Pp / 128), blk, 0, stream>>>(
            feat16, Ff, attWf_t, Ff, Ff, bias_cat, nullptr, featfp, 1024, 1024);
    } else {
        mfma_gemm_staged<true, 1, 0><<<dim3(1024 / 128, Bb * Pp / 128), blk, 0, stream>>>(
            features, Ff, attWf_t, Ff, Ff, bias_cat, nullptr, featfp, 1024, 1024);
    }

    // fprojT for vectorized PV (one-time)
    transpose_fproj_kernel<<<dim3(7, 16, Bb), blk, 0, stream>>>(featfp, fprojT);

    // gates0 emb-part + both biases, hoisted for all t
    mfma_gemm_staged<false, 0, 0><<<dim3(4 * Hh / 128, Tt * Bb / 128), blk, 0, stream>>>(
        xs + Ee, XS, Wemb0, Ee, Ee, b_ih0, b_hh0, g0pre, 4 * Hh, 4 * Hh);

    // ---- sequential decode loop: 5 kernels/step ----
    int cur0 = 0, cur1 = 0;
    for (int t = 0; t < Tt; ++t) {
        ushort* xs_t = xs + (size_t)t * Bb * XS;

        // atth_all[b,a] = h1 @ Wh + bh  (weights read ONCE, tiny MFMA GEMM)
        mfma_gemm_staged<false, 0, 0><<<dim3(Aa / 128, 1), blk, 0, stream>>>(
            h1b[cur1], Hh, attWh_t, Hh, Hh, att_bh, nullptr, atth_all, Aa, Aa);

        att_scores_kernel<<<2 * Bb, dim3(1024), 0, stream>>>(
            featfp, atth_all, att_v, att_bv, scores_g);

        att_pv_kernel<<<2 * Bb, dim3(1024), 0, stream>>>(
            fprojT, scores_g, proj_b, xs_t);

        gates_cell_ksplit<true><<<dim3(8, 32), blk, 0, stream>>>(
            xs_t + Ee + Hh, XS, Wctx0,
            h0b[cur0], Whh0,
            g0pre + (size_t)t * Bb * 4 * Hh, nullptr, nullptr,
            c0, h0b[cur0 ^ 1], nullptr);

        gates_cell_ksplit<false><<<dim3(8, 32), blk, 0, stream>>>(
            h0b[cur0 ^ 1], Hh, Wih1,
            h1b[cur1], Whh1,
            nullptr, b_ih1, b_hh1,
            c1, h1b[cur1 ^ 1], xs_t);
        cur0 ^= 1; cur1 ^= 1;
    }

    // ---- tail: skip GEMM -> LN -> fc GEMM ----
    mfma_gemm_staged<false, 0, 0><<<dim3(Hh / 128, Tt * Bb / 128), blk, 0, stream>>>(
        xs, XS, skipW_t, XS, XS, skip_b, nullptr, skip_pre, Hh, Hh);

    layernorm_kernel<<<Tt * Bb, blk, 0, stream>>>(skip_pre, ln_g, ln_b, ln_all);

    mfma_gemm_staged<false, 2, 1><<<dim3(NFC / 128, Tt * Bb / 128), blk, 0, stream>>>(
        ln_all, Hh, fcW_t, Hh, Hh, fc_b, nullptr, (float*)d_out, Vv, Vv);
}